// Round 15
// baseline (46.583 us; speedup 1.0000x reference)
//
#include <hip/hip_runtime.h>
#include <math.h>

#define KSTEPS 12

typedef float f32x4 __attribute__((ext_vector_type(4)));

// ---- ordered-int <-> float bijection (monotone over finite floats) ----
__device__ __forceinline__ unsigned omap(float f) {
    unsigned u = __float_as_uint(f);
    return (u & 0x80000000u) ? ~u : (u | 0x80000000u);
}
__device__ __forceinline__ float ounmap(unsigned o) {
    unsigned bits = (o & 0x80000000u) ? (o ^ 0x80000000u) : ~o;
    return __uint_as_float(bits);
}

// Full 12-step decision mask for input x, using EXACTLY the arithmetic that
// measured absmax 0.0 vs numpy in rounds 1-14:
//   v = fmaf(-h,z,v)  (== round(v - z*h) since z in {0,1})
//   z = (v > T)       (== sign of (v-T)/(|v|+1), denominator > 0)
__device__ __forceinline__ int sim_mask(float x, const float* hh, const float* TT) {
    float v = x, zf = 0.f;
    int mask = 0;
#pragma unroll
    for (int t = 0; t < KSTEPS; ++t) {
        v  = fmaf(-hh[t], zf, v);
        zf = (v > TT[t]) ? 1.f : 0.f;
        mask |= (v > TT[t] ? 1 : 0) << t;
    }
    return mask;
}

// Setup (1 block, 64 threads; MUST stay single-block — R7 measured the
// per-block-redundant version at +4.3us pure VALU). Bisects the 12 fp-exact
// per-step thresholds (h<=0 => monotone in x => z_t = [x > theta_t]).
//   tbl[0..11]  : thresholds sorted ascending
//   tbl[12..24] : val[k] = fp-exact out value for k spikes, k packed into the
//                 low 4 mantissa bits (error <= 15 ulp ~ 1e-5 << 0.18 thresh)
__global__ void fsc_setup(const float* __restrict__ h, const float* __restrict__ d,
                          const float* __restrict__ T, float* __restrict__ tbl) {
    __shared__ float thRaw[KSTEPS];
    __shared__ int   rank[KSTEPS];
    float hh[KSTEPS], dd[KSTEPS], TT[KSTEPS];
#pragma unroll
    for (int t = 0; t < KSTEPS; ++t) { hh[t] = h[t]; dd[t] = d[t]; TT[t] = T[t]; }

    const int lane = threadIdx.x;
    if (lane < KSTEPS) {
        unsigned lo = omap(-128.0f), hi = omap(128.0f);
        float th;
        if (sim_mask(ounmap(lo), hh, TT) >> lane & 1)         th = -INFINITY;
        else if (!(sim_mask(ounmap(hi), hh, TT) >> lane & 1)) th = INFINITY;
        else {
            while (hi - lo > 1u) {
                unsigned mid = lo + (hi - lo) / 2u;
                if (sim_mask(ounmap(mid), hh, TT) >> lane & 1) hi = mid;
                else                                           lo = mid;
            }
            th = ounmap(lo);
        }
        thRaw[lane] = th;
    }
    __syncthreads();
    if (lane < KSTEPS) {
        const float th = thRaw[lane];
        int r = 0;
#pragma unroll
        for (int j = 0; j < KSTEPS; ++j) {
            const float oj = thRaw[j];
            if (oj < th || (oj == th && j < lane)) r++;
        }
        rank[lane] = r;
        tbl[r] = th;
    }
    __syncthreads();
    if (lane < KSTEPS + 1) {                // level k: spike at the k smallest
        float o = 0.f;
#pragma unroll
        for (int t = 0; t < KSTEPS; ++t) {
            const float zf = (rank[t] < lane) ? 1.f : 0.f;
            o = fmaf(dd[t], zf, o);         // fp-exact reference order
        }
        const unsigned b = (__float_as_uint(o) & ~15u) | (unsigned)lane;
        tbl[KSTEPS + lane] = __uint_as_float(b);
    }
}

__device__ __forceinline__ void chain4(const f32x4 xv, const float* th,
                                       const float* val, f32x4& ov, int& cnt) {
#pragma unroll
    for (int j = 0; j < 4; ++j) {
        const float xj = xv[j];
        float e = val[0];
#pragma unroll
        for (int m = 0; m < KSTEPS; ++m)
            e = (xj > th[m]) ? val[m + 1] : e;
        ov[j] = e;
        cnt += (int)(__float_as_uint(e) & 15u);
    }
}

// Main, ROUND-15 SINGLE CHANGE: dual-stream rolled depth-1 pipeline.
// R12 (rolled depth-1, 1792x7) = 33.6us best; its steady state keeps only
// ~1KB outstanding per wave (~28KB/CU), right at the Little's-law edge
// (24.6 GB/s/CU x ~900ns ~ 22KB) -> latency queueing starves the pipe.
// Here each thread drives TWO independent unit-stride streams (element i of
// each half of x), so every rolled iteration issues 2 coalesced loads +
// 2 stores: 2KB/wave in flight (56KB/CU) with NO unrolled register rotation
// (R13's failure mode). Same grid 1792x256; halves = 3.5 iters/thread ->
// block-uniform split: blocks <896 run 4 iters, blocks >=896 run 3.
__global__ __launch_bounds__(256) void fsc_main(
    const f32x4* __restrict__ x, const float* __restrict__ tbl,
    f32x4* __restrict__ out, float* __restrict__ partial, int n4)
{
    const int tid    = blockIdx.x * blockDim.x + threadIdx.x;
    const int stride = gridDim.x * blockDim.x;
    const int half   = n4 >> 1;             // 1,605,632
    int cnt = 0;

    float th[KSTEPS], val[KSTEPS + 1];
#pragma unroll
    for (int m = 0; m < KSTEPS; ++m) th[m] = tbl[m];        // uniform -> s_load
#pragma unroll
    for (int k = 0; k <= KSTEPS; ++k) val[k] = tbl[KSTEPS + k];

    const f32x4* __restrict__ xB  = x + half;
    f32x4* __restrict__       outB = out + half;

    if (tid < half) {
        // iterations in this half: full + 1 if tid below the remainder
        const int full = half / stride;                  // 3
        const int rem  = half - full * stride;           // 229,376 (= 896 blocks)
        int iters = full + (tid < rem ? 1 : 0);          // block-uniform

        f32x4 curA = __builtin_nontemporal_load(&x[tid]);
        f32x4 curB = __builtin_nontemporal_load(&xB[tid]);
        int i = tid;
        while (--iters > 0) {
            const int ni = i + stride;
            const f32x4 nA = __builtin_nontemporal_load(&x[ni]);   // prefetch
            const f32x4 nB = __builtin_nontemporal_load(&xB[ni]);  // prefetch
            f32x4 ovA, ovB;
            chain4(curA, th, val, ovA, cnt);
            chain4(curB, th, val, ovB, cnt);
            __builtin_nontemporal_store(ovA, &out[i]);
            __builtin_nontemporal_store(ovB, &outB[i]);
            curA = nA; curB = nB; i = ni;
        }
        {   // last iteration
            f32x4 ovA, ovB;
            chain4(curA, th, val, ovA, cnt);
            chain4(curB, th, val, ovB, cnt);
            __builtin_nontemporal_store(ovA, &out[i]);
            __builtin_nontemporal_store(ovB, &outB[i]);
        }
    }

    // spike-count reduce: wave shfl -> LDS -> one exact float per block
    const int lane = threadIdx.x & 63;
    const int wv   = threadIdx.x >> 6;
    __shared__ int smi[4];
#pragma unroll
    for (int off = 32; off > 0; off >>= 1) cnt += __shfl_down(cnt, off);
    if (lane == 0) smi[wv] = cnt;
    __syncthreads();
    if (threadIdx.x == 0)
        partial[blockIdx.x] = (float)(smi[0] + smi[1] + smi[2] + smi[3]);  // exact int
}

__global__ __launch_bounds__(256) void fsc_finalize(
    const float* __restrict__ partial, int nblocks,
    float* __restrict__ out_tail, double inv_n)
{
    double acc = 0.0;
    for (int b = threadIdx.x; b < nblocks; b += blockDim.x)
        acc += (double)partial[b];
    const int lane = threadIdx.x & 63;
    const int wv   = threadIdx.x >> 6;
    __shared__ double sm[4];
#pragma unroll
    for (int off = 32; off > 0; off >>= 1) acc += __shfl_down(acc, off);
    if (lane == 0) sm[wv] = acc;
    __syncthreads();
    if (threadIdx.x == 0) {
        const double tot = sm[0] + sm[1] + sm[2] + sm[3];   // exact integer
        out_tail[0] = 0.0f;                  // v_reg: analytically zero (|T|<1)
        out_tail[1] = (float)(tot * inv_n);  // z_reg
    }
}

extern "C" void kernel_launch(void* const* d_in, const int* in_sizes, int n_in,
                              void* d_out, int out_size, void* d_ws, size_t ws_size,
                              hipStream_t stream) {
    const f32x4*  x    = (const f32x4*)d_in[0];
    const float*  h    = (const float*)d_in[1];
    const float*  dpar = (const float*)d_in[2];
    const float*  T    = (const float*)d_in[3];
    float* out = (float*)d_out;

    const int n  = in_sizes[0];   // 12,845,056
    const int n4 = n / 4;         // 3,211,264
    const int blocks = 1792;      // stride 458,752; half = 3.5x -> 4/3 split

    float* tbl     = (float*)d_ws;        // 25 floats
    float* partial = (float*)d_ws + 64;   // `blocks` floats

    fsc_setup   <<<1,      64,  0, stream>>>(h, dpar, T, tbl);
    fsc_main    <<<blocks, 256, 0, stream>>>(x, tbl, (f32x4*)out, partial, n4);
    fsc_finalize<<<1,      256, 0, stream>>>(partial, blocks, out + n, 1.0 / (double)n);
}

// Round 16
// 34.706 us; speedup vs baseline: 1.3422x; 1.3422x over previous
//
#include <hip/hip_runtime.h>
#include <math.h>

#define KSTEPS 12

typedef float f32x4 __attribute__((ext_vector_type(4)));

// ---- ordered-int <-> float bijection (monotone over finite floats) ----
__device__ __forceinline__ unsigned omap(float f) {
    unsigned u = __float_as_uint(f);
    return (u & 0x80000000u) ? ~u : (u | 0x80000000u);
}
__device__ __forceinline__ float ounmap(unsigned o) {
    unsigned bits = (o & 0x80000000u) ? (o ^ 0x80000000u) : ~o;
    return __uint_as_float(bits);
}

// Full 12-step decision mask for input x, using EXACTLY the arithmetic that
// measured absmax 0.0 vs numpy in rounds 1-15:
//   v = fmaf(-h,z,v)  (== round(v - z*h) since z in {0,1})
//   z = (v > T)       (== sign of (v-T)/(|v|+1), denominator > 0)
__device__ __forceinline__ int sim_mask(float x, const float* hh, const float* TT) {
    float v = x, zf = 0.f;
    int mask = 0;
#pragma unroll
    for (int t = 0; t < KSTEPS; ++t) {
        v  = fmaf(-hh[t], zf, v);
        zf = (v > TT[t]) ? 1.f : 0.f;
        mask |= (v > TT[t] ? 1 : 0) << t;
    }
    return mask;
}

// Setup (1 block, 64 threads; MUST stay single-block — R7 measured the
// per-block-redundant version at +4.3us pure VALU). Bisects the 12 fp-exact
// per-step thresholds (h<=0 => monotone in x => z_t = [x > theta_t]).
//   tbl[0..11]  : thresholds sorted ascending
//   tbl[12..24] : val[k] = fp-exact out value for k spikes, k packed into the
//                 low 4 mantissa bits (error <= 15 ulp ~ 1e-5 << 0.18 thresh)
__global__ void fsc_setup(const float* __restrict__ h, const float* __restrict__ d,
                          const float* __restrict__ T, float* __restrict__ tbl) {
    __shared__ float thRaw[KSTEPS];
    __shared__ int   rank[KSTEPS];
    float hh[KSTEPS], dd[KSTEPS], TT[KSTEPS];
#pragma unroll
    for (int t = 0; t < KSTEPS; ++t) { hh[t] = h[t]; dd[t] = d[t]; TT[t] = T[t]; }

    const int lane = threadIdx.x;
    if (lane < KSTEPS) {
        unsigned lo = omap(-128.0f), hi = omap(128.0f);
        float th;
        if (sim_mask(ounmap(lo), hh, TT) >> lane & 1)         th = -INFINITY;
        else if (!(sim_mask(ounmap(hi), hh, TT) >> lane & 1)) th = INFINITY;
        else {
            while (hi - lo > 1u) {
                unsigned mid = lo + (hi - lo) / 2u;
                if (sim_mask(ounmap(mid), hh, TT) >> lane & 1) hi = mid;
                else                                           lo = mid;
            }
            th = ounmap(lo);
        }
        thRaw[lane] = th;
    }
    __syncthreads();
    if (lane < KSTEPS) {
        const float th = thRaw[lane];
        int r = 0;
#pragma unroll
        for (int j = 0; j < KSTEPS; ++j) {
            const float oj = thRaw[j];
            if (oj < th || (oj == th && j < lane)) r++;
        }
        rank[lane] = r;
        tbl[r] = th;
    }
    __syncthreads();
    if (lane < KSTEPS + 1) {                // level k: spike at the k smallest
        float o = 0.f;
#pragma unroll
        for (int t = 0; t < KSTEPS; ++t) {
            const float zf = (rank[t] < lane) ? 1.f : 0.f;
            o = fmaf(dd[t], zf, o);         // fp-exact reference order
        }
        const unsigned b = (__float_as_uint(o) & ~15u) | (unsigned)lane;
        tbl[KSTEPS + lane] = __uint_as_float(b);
    }
}

// Main: the R12 optimum, restored verbatim — rolled depth-1 software-
// pipelined grid-stride loop, 1792 blocks x 256 thr x 7 iters. Every probed
// deviation regressed: unrolled depth-2 (+23us), fewer blocks (+3), dual
// stream (+13), one-shot flat (+9), fused finalize w/ atomics (+50),
// inlined setup (+4); store/load cache flavor and ITERS are neutral.
__global__ __launch_bounds__(256) void fsc_main(
    const f32x4* __restrict__ x, const float* __restrict__ tbl,
    f32x4* __restrict__ out, float* __restrict__ partial, int n4)
{
    const int tid    = blockIdx.x * blockDim.x + threadIdx.x;
    const int stride = gridDim.x * blockDim.x;
    int cnt = 0;

    float th[KSTEPS], val[KSTEPS + 1];
#pragma unroll
    for (int m = 0; m < KSTEPS; ++m) th[m] = tbl[m];        // uniform -> s_load
#pragma unroll
    for (int k = 0; k <= KSTEPS; ++k) val[k] = tbl[KSTEPS + k];

    if (tid < n4) {
        f32x4 cur = __builtin_nontemporal_load(&x[tid]);
        int i = tid, nxt_i = tid + stride;
        while (nxt_i < n4) {
            const f32x4 nxt = __builtin_nontemporal_load(&x[nxt_i]);  // prefetch
            f32x4 ov;
#pragma unroll
            for (int j = 0; j < 4; ++j) {
                const float xj = cur[j];
                float e = val[0];
#pragma unroll
                for (int m = 0; m < KSTEPS; ++m)
                    e = (xj > th[m]) ? val[m + 1] : e;
                ov[j] = e;
                cnt += (int)(__float_as_uint(e) & 15u);
            }
            __builtin_nontemporal_store(ov, &out[i]);
            cur = nxt; i = nxt_i; nxt_i += stride;
        }
        {   // last iteration
            f32x4 ov;
#pragma unroll
            for (int j = 0; j < 4; ++j) {
                const float xj = cur[j];
                float e = val[0];
#pragma unroll
                for (int m = 0; m < KSTEPS; ++m)
                    e = (xj > th[m]) ? val[m + 1] : e;
                ov[j] = e;
                cnt += (int)(__float_as_uint(e) & 15u);
            }
            __builtin_nontemporal_store(ov, &out[i]);
        }
    }

    // spike-count reduce: wave shfl -> LDS -> one exact float per block
    const int lane = threadIdx.x & 63;
    const int wv   = threadIdx.x >> 6;
    __shared__ int smi[4];
#pragma unroll
    for (int off = 32; off > 0; off >>= 1) cnt += __shfl_down(cnt, off);
    if (lane == 0) smi[wv] = cnt;
    __syncthreads();
    if (threadIdx.x == 0)
        partial[blockIdx.x] = (float)(smi[0] + smi[1] + smi[2] + smi[3]);  // exact int
}

__global__ __launch_bounds__(256) void fsc_finalize(
    const float* __restrict__ partial, int nblocks,
    float* __restrict__ out_tail, double inv_n)
{
    double acc = 0.0;
    for (int b = threadIdx.x; b < nblocks; b += blockDim.x)
        acc += (double)partial[b];
    const int lane = threadIdx.x & 63;
    const int wv   = threadIdx.x >> 6;
    __shared__ double sm[4];
#pragma unroll
    for (int off = 32; off > 0; off >>= 1) acc += __shfl_down(acc, off);
    if (lane == 0) sm[wv] = acc;
    __syncthreads();
    if (threadIdx.x == 0) {
        const double tot = sm[0] + sm[1] + sm[2] + sm[3];   // exact integer
        out_tail[0] = 0.0f;                  // v_reg: analytically zero (|T|<1)
        out_tail[1] = (float)(tot * inv_n);  // z_reg
    }
}

extern "C" void kernel_launch(void* const* d_in, const int* in_sizes, int n_in,
                              void* d_out, int out_size, void* d_ws, size_t ws_size,
                              hipStream_t stream) {
    const f32x4*  x    = (const f32x4*)d_in[0];
    const float*  h    = (const float*)d_in[1];
    const float*  dpar = (const float*)d_in[2];
    const float*  T    = (const float*)d_in[3];
    float* out = (float*)d_out;

    const int n  = in_sizes[0];   // 12,845,056
    const int n4 = n / 4;         // 3,211,264 = 1792 * 256 * 7 exactly
    const int blocks = 1792;      // 7 blocks/CU, 7 pipelined iters/thread

    float* tbl     = (float*)d_ws;        // 25 floats
    float* partial = (float*)d_ws + 64;   // `blocks` floats

    fsc_setup   <<<1,      64,  0, stream>>>(h, dpar, T, tbl);
    fsc_main    <<<blocks, 256, 0, stream>>>(x, tbl, (f32x4*)out, partial, n4);
    fsc_finalize<<<1,      256, 0, stream>>>(partial, blocks, out + n, 1.0 / (double)n);
}